// Round 6
// baseline (179.446 us; speedup 1.0000x reference)
//
#include <hip/hip_runtime.h>
#include <stdint.h>

typedef __attribute__((ext_vector_type(4))) int i32x4;
typedef __attribute__((ext_vector_type(16))) float f32x16;

#define MROWS 8192L
#define NCOLS 4096L
#define KDIM  4096L

#define XQ_BYTES   (MROWS * KDIM / 2)            // 16777216 (fp4: 2048 B/row)
#define WQ_BYTES   (NCOLS * KDIM / 2)            // 8388608
#define SCAL_OFF   (XQ_BYTES + WQ_BYTES)

// ---------------- reduction: sum|x| (blocks 0..511), sum|w| (blocks 512..767) ----
__global__ __launch_bounds__(256) void k_reduce_abs(const float* __restrict__ x,
                                                    const float* __restrict__ w,
                                                    float* __restrict__ partials) {
    __shared__ float sm[256];
    int b = blockIdx.x;
    int t = threadIdx.x;
    const float4* v;
    long base;
    if (b < 512) { v = (const float4*)x; base = (long)b * 16384; }
    else         { v = (const float4*)w; base = (long)(b - 512) * 16384; }
    float s = 0.f;
    for (int i = t; i < 16384; i += 256) {
        float4 q = v[base + i];
        s += fabsf(q.x) + fabsf(q.y) + fabsf(q.z) + fabsf(q.w);
    }
    sm[t] = s;
    __syncthreads();
    for (int off = 128; off > 0; off >>= 1) {
        if (t < off) sm[t] += sm[t + off];
        __syncthreads();
    }
    if (t == 0) partials[b] = sm[0];
}

// ---------------- finalize: double-precision combine, write scalars --------------
__global__ __launch_bounds__(256) void k_finalize(float* __restrict__ scal) {
    const float* partials = scal + 4;
    __shared__ double sm[256];
    int t = threadIdx.x;

    double sx = 0.0;
    for (int i = t; i < 512; i += 256) sx += (double)partials[i];
    sm[t] = sx;
    __syncthreads();
    for (int off = 128; off > 0; off >>= 1) {
        if (t < off) sm[t] += sm[t + off];
        __syncthreads();
    }
    double SX = sm[0];
    __syncthreads();

    double sw = (double)partials[512 + t];
    sm[t] = sw;
    __syncthreads();
    for (int off = 128; off > 0; off >>= 1) {
        if (t < off) sm[t] += sm[t + off];
        __syncthreads();
    }
    if (t == 0) {
        float meanx = (float)(SX / 33554432.0);
        float meanw = (float)(sm[0] / 16777216.0);
        scal[0] = 0.1f * meanx;   // delta_x
        scal[1] = 0.05f * meanw;  // delta_w
        scal[2] = meanw;          // alpha
    }
}

// ---------------- ternarize to fp4 e2m1 {-1,0,1}: 8 floats -> 1 uint -------------
__device__ __forceinline__ unsigned int nib4(float v, float delta) {
    return v > delta ? 2u : (v < -delta ? 10u : 0u);   // +1=0x2, -1=0xA, 0=0x0
}

// merged x+w quantization (blocks [0,2048): x, [2048,3072): w)
__global__ __launch_bounds__(256) void k_quant4(const float* __restrict__ x,
                                                const float* __restrict__ w,
                                                unsigned int* __restrict__ xq,
                                                unsigned int* __restrict__ wq,
                                                const float* __restrict__ scal) {
    int b = blockIdx.x;
    const float* src;
    unsigned int* dst;
    float delta;
    long i0, stride, total8;
    if (b < 2048) {
        src = x; dst = xq; delta = scal[0];
        i0 = (long)b * 256 + threadIdx.x; stride = 2048L * 256; total8 = MROWS * KDIM / 8;
    } else {
        src = w; dst = wq; delta = scal[1];
        i0 = (long)(b - 2048) * 256 + threadIdx.x; stride = 1024L * 256; total8 = NCOLS * KDIM / 8;
    }
    const float4* s4 = (const float4*)src;
    for (long i = i0; i < total8; i += stride) {
        float4 q0 = s4[2 * i];
        float4 q1 = s4[2 * i + 1];
        unsigned int wd = nib4(q0.x, delta)
                        | (nib4(q0.y, delta) << 4)
                        | (nib4(q0.z, delta) << 8)
                        | (nib4(q0.w, delta) << 12)
                        | (nib4(q1.x, delta) << 16)
                        | (nib4(q1.y, delta) << 20)
                        | (nib4(q1.z, delta) << 24)
                        | (nib4(q1.w, delta) << 28);
        dst[i] = wd;
    }
}

// ---- GEMM: out = alpha * (Xq @ Wq^T), fp4 32x32x64 MFMA, fragment-major LDS -----
#define GLOAD_LDS16(g, l)                                                             \
    __builtin_amdgcn_global_load_lds((const __attribute__((address_space(1))) void*)(g), \
                                     (__attribute__((address_space(3))) void*)(l),       \
                                     16, 0, 0)

// i32x4 -> i32x8 with undef high half (fp4 data occupies low 4 VGPRs)
#define MK8(v) __builtin_shufflevector((v), (v), 0, 1, 2, 3, -1, -1, -1, -1)

// fp4 x fp4, scales = 1.0 (E8M0 127 in every byte)
#define MFMA32(a, b, c)                                                       \
    __builtin_amdgcn_mfma_scale_f32_32x32x64_f8f6f4(MK8(a), MK8(b), (c),      \
        4, 4, 0, 0x7F7F7F7F, 0, 0x7F7F7F7F)

__global__ __launch_bounds__(512, 2) void k_gemm(const signed char* __restrict__ Xq,
                                                 const signed char* __restrict__ Wq,
                                                 float* __restrict__ out,
                                                 const float* __restrict__ scal) {
    // ring of 4 K-tile slots, each 32 KB fragment-major:
    //   A groups g=0..15:  [wm(2)][mi(4)][ks(2)] x (64 lanes x 16 B)
    //   B groups g=16..31: [wn(4)][ni(2)][ks(2)] x (64 lanes x 16 B)
    __shared__ __attribute__((aligned(16))) signed char lds[131072];

    const float alpha = scal[2];

    // XCD-aware bijective swizzle (512 blocks, 512 % 8 == 0, cpx = 64)
    int bid = (int)blockIdx.x;
    bid = (bid & 7) * 64 + (bid >> 3);
    int bm = bid >> 4;                 // 0..31  (M/256)
    int bn = bid & 15;                 // 0..15  (N/256)
    long row0 = (long)bm * 256;
    long col0 = (long)bn * 256;

    int t = threadIdx.x;               // 0..511
    int lane = t & 63;
    int wid = t >> 6;                  // 0..7
    int wm = wid >> 2;                 // 0..1  (M half: 128 rows)
    int wn = wid & 3;                  // 0..3  (N quarter: 64 cols)

    // ---- staging: each wave stages 4 fragment groups (g = wid*4 + j) ----
    // group g -> source element: row (lane&31), k-half (lane>>5) of the fragment
    const signed char* sp[4];
    int ldoff[4];
#pragma unroll
    for (int j = 0; j < 4; ++j) {
        int g = wid * 4 + j;
        ldoff[j] = g * 1024;
        if (g < 16) {   // A fragment group: wm=g>>3, mi=(g>>1)&3, ks=g&1
            long grow = row0 + (g >> 3) * 128 + ((g >> 1) & 3) * 32 + (lane & 31);
            sp[j] = Xq + grow * 2048 + (g & 1) * 32 + (lane >> 5) * 16;
        } else {        // B fragment group: h=g-16, wn=h>>2, ni=(h>>1)&1, ks=h&1
            int h = g - 16;
            long grow = col0 + (h >> 2) * 64 + ((h >> 1) & 1) * 32 + (lane & 31);
            sp[j] = Wq + grow * 2048 + (h & 1) * 32 + (lane >> 5) * 16;
        }
    }

#define STAGE(slot, g1) do {                                                   \
    signed char* sb_ = lds + (slot) * 32768;                                   \
    _Pragma("unroll")                                                          \
    for (int j_ = 0; j_ < 4; ++j_)                                             \
        GLOAD_LDS16(sp[j_] + (long)(g1) * 64, sb_ + ldoff[j_]);                \
} while (0)

    // ---- fragment read addressing: uniform base + lane*16 + imm offset ----
    const signed char* Ab = lds + wm * 8192 + lane * 16;            // + slot*32768 + (mi*2+ks)*1024
    const signed char* Bb = lds + 16384 + wn * 4096 + lane * 16;    // + slot*32768 + (ni*2+ks)*1024

    f32x16 acc[4][2];
#pragma unroll
    for (int i = 0; i < 4; ++i)
#pragma unroll
        for (int j = 0; j < 2; ++j)
            acc[i][j] = (f32x16){0.f};

    // prologue: stage K-tiles 0,1,2 into slots 0,1,2 (12 loads in flight)
    STAGE(0, 0);
    STAGE(1, 1);
    STAGE(2, 2);

    for (int g = 0; g < 32; ++g) {
        int slot = g & 3;
        // B1: all waves done reading slot (g+3)&3's old contents (tile g-1)
        __builtin_amdgcn_s_barrier();
        if (g < 29) {
            STAGE((g + 3) & 3, g + 3);                             // issue-early
            asm volatile("s_waitcnt vmcnt(12)" ::: "memory");      // tile g landed
        } else if (g == 29) {
            asm volatile("s_waitcnt vmcnt(8)" ::: "memory");
        } else if (g == 30) {
            asm volatile("s_waitcnt vmcnt(4)" ::: "memory");
        } else {
            asm volatile("s_waitcnt vmcnt(0)" ::: "memory");
        }
        // B2: publish "tile g fully landed" to all waves
        __builtin_amdgcn_s_barrier();
        __builtin_amdgcn_sched_barrier(0);

        const signed char* A = Ab + slot * 32768;
        const signed char* B = Bb + slot * 32768;

        i32x4 a00, a01, a10, a11, a20, a21, a30, a31;
        i32x4 b00, b01, b10, b11;
        // reads: B all, A mi0-1
        b00 = *(const i32x4*)(B + 0 * 1024);
        b01 = *(const i32x4*)(B + 1 * 1024);
        b10 = *(const i32x4*)(B + 2 * 1024);
        b11 = *(const i32x4*)(B + 3 * 1024);
        a00 = *(const i32x4*)(A + 0 * 1024);
        a01 = *(const i32x4*)(A + 1 * 1024);
        a10 = *(const i32x4*)(A + 2 * 1024);
        a11 = *(const i32x4*)(A + 3 * 1024);
        __builtin_amdgcn_s_setprio(1);
        acc[0][0] = MFMA32(a00, b00, acc[0][0]);
        acc[0][1] = MFMA32(a00, b10, acc[0][1]);
        acc[1][0] = MFMA32(a10, b00, acc[1][0]);
        acc[1][1] = MFMA32(a10, b10, acc[1][1]);
        acc[0][0] = MFMA32(a01, b01, acc[0][0]);
        acc[0][1] = MFMA32(a01, b11, acc[0][1]);
        acc[1][0] = MFMA32(a11, b01, acc[1][0]);
        acc[1][1] = MFMA32(a11, b11, acc[1][1]);
        __builtin_amdgcn_s_setprio(0);
        // reads: A mi2-3
        a20 = *(const i32x4*)(A + 4 * 1024);
        a21 = *(const i32x4*)(A + 5 * 1024);
        a30 = *(const i32x4*)(A + 6 * 1024);
        a31 = *(const i32x4*)(A + 7 * 1024);
        __builtin_amdgcn_s_setprio(1);
        acc[2][0] = MFMA32(a20, b00, acc[2][0]);
        acc[2][1] = MFMA32(a20, b10, acc[2][1]);
        acc[3][0] = MFMA32(a30, b00, acc[3][0]);
        acc[3][1] = MFMA32(a30, b10, acc[3][1]);
        acc[2][0] = MFMA32(a21, b01, acc[2][0]);
        acc[2][1] = MFMA32(a21, b11, acc[2][1]);
        acc[3][0] = MFMA32(a31, b01, acc[3][0]);
        acc[3][1] = MFMA32(a31, b11, acc[3][1]);
        __builtin_amdgcn_s_setprio(0);
    }

    // epilogue: 32x32 C/D mapping: col = lane&31, row = (r&3) + 8*(r>>2) + 4*(lane>>5)
#pragma unroll
    for (int mi = 0; mi < 4; ++mi) {
#pragma unroll
        for (int ni = 0; ni < 2; ++ni) {
            long col = col0 + wn * 64 + ni * 32 + (lane & 31);
            long rowb = row0 + wm * 128 + mi * 32 + 4 * (lane >> 5);
#pragma unroll
            for (int r = 0; r < 16; ++r) {
                long row = rowb + (r & 3) + 8 * (r >> 2);
                out[row * NCOLS + col] = alpha * acc[mi][ni][r];
            }
        }
    }
#undef STAGE
}

// ---------------- host launch ----------------------------------------------------
extern "C" void kernel_launch(void* const* d_in, const int* in_sizes, int n_in,
                              void* d_out, int out_size, void* d_ws, size_t ws_size,
                              hipStream_t stream) {
    const float* x = (const float*)d_in[0];   // 8192 x 4096 f32
    const float* w = (const float*)d_in[1];   // 4096 x 4096 f32
    float* out = (float*)d_out;               // 8192 x 4096 f32

    uint8_t* ws = (uint8_t*)d_ws;
    signed char* Xq = (signed char*)ws;                  // fp4 ternary x (16 MB)
    signed char* Wq = (signed char*)(ws + XQ_BYTES);     // fp4 ternary w (8 MB)
    float* scal = (float*)(ws + SCAL_OFF);               // [delta_x, delta_w, alpha, pad]
    // partials at scal+4 (768 floats)

    k_reduce_abs<<<768, 256, 0, stream>>>(x, w, scal + 4);
    k_finalize<<<1, 256, 0, stream>>>(scal);
    k_quant4<<<3072, 256, 0, stream>>>(x, w, (unsigned int*)Xq, (unsigned int*)Wq, scal);
    k_gemm<<<512, 512, 0, stream>>>(Xq, Wq, out, scal);
}

// Round 7
// 156.333 us; speedup vs baseline: 1.1478x; 1.1478x over previous
//
#include <hip/hip_runtime.h>
#include <stdint.h>

typedef __attribute__((ext_vector_type(4))) int i32x4;
typedef __attribute__((ext_vector_type(16))) float f32x16;

#define MROWS 8192L
#define NCOLS 4096L
#define KDIM  4096L

#define XQ_BYTES   (MROWS * KDIM / 2)            // 16777216 (fp4, fragment-permuted)
#define WQ_BYTES   (NCOLS * KDIM / 2)            // 8388608
#define SCAL_OFF   (XQ_BYTES + WQ_BYTES)

// ---------------- reduction: sum|x| (blocks 0..511), sum|w| (blocks 512..767) ----
__global__ __launch_bounds__(256) void k_reduce_abs(const float* __restrict__ x,
                                                    const float* __restrict__ w,
                                                    float* __restrict__ partials) {
    __shared__ float sm[256];
    int b = blockIdx.x;
    int t = threadIdx.x;
    const float4* v;
    long base;
    if (b < 512) { v = (const float4*)x; base = (long)b * 16384; }
    else         { v = (const float4*)w; base = (long)(b - 512) * 16384; }
    float s = 0.f;
    for (int i = t; i < 16384; i += 256) {
        float4 q = v[base + i];
        s += fabsf(q.x) + fabsf(q.y) + fabsf(q.z) + fabsf(q.w);
    }
    sm[t] = s;
    __syncthreads();
    for (int off = 128; off > 0; off >>= 1) {
        if (t < off) sm[t] += sm[t + off];
        __syncthreads();
    }
    if (t == 0) partials[b] = sm[0];
}

// ---------------- finalize: double-precision combine, write scalars --------------
__global__ __launch_bounds__(256) void k_finalize(float* __restrict__ scal) {
    const float* partials = scal + 4;
    __shared__ double sm[256];
    int t = threadIdx.x;

    double sx = 0.0;
    for (int i = t; i < 512; i += 256) sx += (double)partials[i];
    sm[t] = sx;
    __syncthreads();
    for (int off = 128; off > 0; off >>= 1) {
        if (t < off) sm[t] += sm[t + off];
        __syncthreads();
    }
    double SX = sm[0];
    __syncthreads();

    double sw = (double)partials[512 + t];
    sm[t] = sw;
    __syncthreads();
    for (int off = 128; off > 0; off >>= 1) {
        if (t < off) sm[t] += sm[t + off];
        __syncthreads();
    }
    if (t == 0) {
        float meanx = (float)(SX / 33554432.0);
        float meanw = (float)(sm[0] / 16777216.0);
        scal[0] = 0.1f * meanx;   // delta_x
        scal[1] = 0.05f * meanw;  // delta_w
        scal[2] = meanw;          // alpha
    }
}

// ---------------- ternarize to fp4 e2m1 {-1,0,1}, fragment-permuted output -------
// Layout (X): 1KB block BX = (rowblk*32 + ktile)*2 + ks ; inside: [khalf(2)][r32(32)][16B]
//   element (row, k): rowblk=row/32, r32=row%32, ktile=k/128, ks=(k/64)&1,
//                     khalf=(k/32)&1, kin=k%32 -> byte BX*1024 + khalf*512 + r32*16 + kin/2
// One wave produces one 1KB block: lane l -> khalf=l>>5, r32=l&31, 32 consecutive k.
__device__ __forceinline__ unsigned int nib4(float v, float delta) {
    return v > delta ? 2u : (v < -delta ? 10u : 0u);   // +1=0x2, -1=0xA, 0=0x0
}

__global__ __launch_bounds__(256) void k_quantF(const float* __restrict__ x,
                                                const float* __restrict__ w,
                                                uint4* __restrict__ xq,
                                                uint4* __restrict__ wq,
                                                const float* __restrict__ scal) {
    int wv = blockIdx.x * 4 + (threadIdx.x >> 6);   // wave task id, 0..24575
    int l = threadIdx.x & 63;

    const float* src;
    uint4* dst;
    float delta;
    int task;                        // block index within its tensor
    if (wv < 16384) {                // X: rowblk(256) x ktile(32) x ks(2)
        src = x; dst = xq; delta = scal[0]; task = wv;
    } else {                         // W: colblk(128) x ktile(32) x ks(2)
        src = w; dst = wq; delta = scal[1]; task = wv - 16384;
    }
    int rowblk = task >> 6;
    int rest = task & 63;            // ktile*2 + ks
    long row = (long)rowblk * 32 + (l & 31);
    long fidx = row * 4096 + (long)(rest >> 1) * 128 + (long)(rest & 1) * 64
              + (long)(l >> 5) * 32;
    const float4* s4 = (const float4*)(src + fidx);

    unsigned int ow[4];
#pragma unroll
    for (int c = 0; c < 4; ++c) {
        float4 q0 = s4[2 * c];
        float4 q1 = s4[2 * c + 1];
        ow[c] = nib4(q0.x, delta)
              | (nib4(q0.y, delta) << 4)
              | (nib4(q0.z, delta) << 8)
              | (nib4(q0.w, delta) << 12)
              | (nib4(q1.x, delta) << 16)
              | (nib4(q1.y, delta) << 20)
              | (nib4(q1.z, delta) << 24)
              | (nib4(q1.w, delta) << 28);
    }
    uint4 o; o.x = ow[0]; o.y = ow[1]; o.z = ow[2]; o.w = ow[3];
    dst[(long)task * 64 + l] = o;    // 64 lanes x 16B = contiguous 1KB
}

// ---- GEMM: out = alpha * (Xq @ Wq^T), fp4 32x32x64 MFMA, fragment-major LDS -----
#define GLOAD_LDS16(g, l)                                                             \
    __builtin_amdgcn_global_load_lds((const __attribute__((address_space(1))) void*)(g), \
                                     (__attribute__((address_space(3))) void*)(l),       \
                                     16, 0, 0)

// i32x4 -> i32x8 with undef high half (fp4 data occupies low 4 VGPRs)
#define MK8(v) __builtin_shufflevector((v), (v), 0, 1, 2, 3, -1, -1, -1, -1)

// fp4 x fp4, scales = 1.0 (E8M0 127 in every byte)
#define MFMA32(a, b, c)                                                       \
    __builtin_amdgcn_mfma_scale_f32_32x32x64_f8f6f4(MK8(a), MK8(b), (c),      \
        4, 4, 0, 0x7F7F7F7F, 0, 0x7F7F7F7F)

__global__ __launch_bounds__(512, 2) void k_gemm(const signed char* __restrict__ Xq,
                                                 const signed char* __restrict__ Wq,
                                                 float* __restrict__ out,
                                                 const float* __restrict__ scal) {
    // ring of 4 K-tile slots, each 32 KB fragment-major:
    //   A groups g=0..15:  [wm(2)][mi(4)][ks(2)] x (64 lanes x 16 B)
    //   B groups g=16..31: [wn(4)][ni(2)][ks(2)] x (64 lanes x 16 B)
    __shared__ __attribute__((aligned(16))) signed char lds[131072];

    const float alpha = scal[2];

    // XCD-aware bijective swizzle (512 blocks, 512 % 8 == 0, cpx = 64)
    int bid = (int)blockIdx.x;
    bid = (bid & 7) * 64 + (bid >> 3);
    int bm = bid >> 4;                 // 0..31  (M/256)
    int bn = bid & 15;                 // 0..15  (N/256)
    long row0 = (long)bm * 256;
    long col0 = (long)bn * 256;

    int t = threadIdx.x;               // 0..511
    int lane = t & 63;
    int wid = t >> 6;                  // 0..7
    int wm = wid >> 2;                 // 0..1  (M half: 128 rows)
    int wn = wid & 3;                  // 0..3  (N quarter: 64 cols)

    // ---- staging: each wave stages 4 fragment groups (g = wid*4 + j) ----
    // source is PRE-PERMUTED: block (rowblk*32 + g1)*2 + ks, lane-contiguous 1KB
    const signed char* sp[4];
    int ldoff[4];
#pragma unroll
    for (int j = 0; j < 4; ++j) {
        int g = wid * 4 + j;
        ldoff[j] = g * 1024;
        if (g < 16) {   // A: wm=g>>3, mi=(g>>1)&3, ks=g&1
            long rowblk = bm * 8 + (g >> 3) * 4 + ((g >> 1) & 3);
            sp[j] = Xq + rowblk * 65536 + (g & 1) * 1024 + lane * 16;
        } else {        // B: h=g-16, wn=h>>2, ni=(h>>1)&1, ks=h&1
            int h = g - 16;
            long colblk = bn * 8 + (h >> 2) * 2 + ((h >> 1) & 1);
            sp[j] = Wq + colblk * 65536 + (h & 1) * 1024 + lane * 16;
        }
    }

#define STAGE(slot, g1) do {                                                   \
    signed char* sb_ = lds + (slot) * 32768;                                   \
    _Pragma("unroll")                                                          \
    for (int j_ = 0; j_ < 4; ++j_)                                             \
        GLOAD_LDS16(sp[j_] + (long)(g1) * 2048, sb_ + ldoff[j_]);              \
} while (0)

    // ---- fragment read addressing: uniform base + lane*16 + imm offset ----
    const signed char* Ab = lds + wm * 8192 + lane * 16;            // + slot*32768 + (mi*2+ks)*1024
    const signed char* Bb = lds + 16384 + wn * 4096 + lane * 16;    // + slot*32768 + (ni*2+ks)*1024

    f32x16 acc[4][2];
#pragma unroll
    for (int i = 0; i < 4; ++i)
#pragma unroll
        for (int j = 0; j < 2; ++j)
            acc[i][j] = (f32x16){0.f};

    // prologue: stage K-tiles 0,1,2 into slots 0,1,2 (12 loads in flight)
    STAGE(0, 0);
    STAGE(1, 1);
    STAGE(2, 2);

    for (int g = 0; g < 32; ++g) {
        int slot = g & 3;
        // B1: all waves done reading slot (g+3)&3's old contents (tile g-1)
        __builtin_amdgcn_s_barrier();
        if (g < 29) {
            STAGE((g + 3) & 3, g + 3);                             // issue-early
            asm volatile("s_waitcnt vmcnt(12)" ::: "memory");      // tile g landed
        } else if (g == 29) {
            asm volatile("s_waitcnt vmcnt(8)" ::: "memory");
        } else if (g == 30) {
            asm volatile("s_waitcnt vmcnt(4)" ::: "memory");
        } else {
            asm volatile("s_waitcnt vmcnt(0)" ::: "memory");
        }
        // B2: publish "tile g fully landed" to all waves
        __builtin_amdgcn_s_barrier();
        __builtin_amdgcn_sched_barrier(0);

        const signed char* A = Ab + slot * 32768;
        const signed char* B = Bb + slot * 32768;

        i32x4 a00, a01, a10, a11, a20, a21, a30, a31;
        i32x4 b00, b01, b10, b11;
        // reads: B all, A mi0-1
        b00 = *(const i32x4*)(B + 0 * 1024);
        b01 = *(const i32x4*)(B + 1 * 1024);
        b10 = *(const i32x4*)(B + 2 * 1024);
        b11 = *(const i32x4*)(B + 3 * 1024);
        a00 = *(const i32x4*)(A + 0 * 1024);
        a01 = *(const i32x4*)(A + 1 * 1024);
        a10 = *(const i32x4*)(A + 2 * 1024);
        a11 = *(const i32x4*)(A + 3 * 1024);
        __builtin_amdgcn_s_setprio(1);
        acc[0][0] = MFMA32(a00, b00, acc[0][0]);
        acc[0][1] = MFMA32(a00, b10, acc[0][1]);
        acc[1][0] = MFMA32(a10, b00, acc[1][0]);
        acc[1][1] = MFMA32(a10, b10, acc[1][1]);
        acc[0][0] = MFMA32(a01, b01, acc[0][0]);
        acc[0][1] = MFMA32(a01, b11, acc[0][1]);
        acc[1][0] = MFMA32(a11, b01, acc[1][0]);
        acc[1][1] = MFMA32(a11, b11, acc[1][1]);
        __builtin_amdgcn_s_setprio(0);
        // reads: A mi2-3
        a20 = *(const i32x4*)(A + 4 * 1024);
        a21 = *(const i32x4*)(A + 5 * 1024);
        a30 = *(const i32x4*)(A + 6 * 1024);
        a31 = *(const i32x4*)(A + 7 * 1024);
        __builtin_amdgcn_s_setprio(1);
        acc[2][0] = MFMA32(a20, b00, acc[2][0]);
        acc[2][1] = MFMA32(a20, b10, acc[2][1]);
        acc[3][0] = MFMA32(a30, b00, acc[3][0]);
        acc[3][1] = MFMA32(a30, b10, acc[3][1]);
        acc[2][0] = MFMA32(a21, b01, acc[2][0]);
        acc[2][1] = MFMA32(a21, b11, acc[2][1]);
        acc[3][0] = MFMA32(a31, b01, acc[3][0]);
        acc[3][1] = MFMA32(a31, b11, acc[3][1]);
        __builtin_amdgcn_s_setprio(0);
    }

    // epilogue: 32x32 C/D mapping: col = lane&31, row = (r&3) + 8*(r>>2) + 4*(lane>>5)
#pragma unroll
    for (int mi = 0; mi < 4; ++mi) {
#pragma unroll
        for (int ni = 0; ni < 2; ++ni) {
            long col = col0 + wn * 64 + ni * 32 + (lane & 31);
            long rowb = row0 + wm * 128 + mi * 32 + 4 * (lane >> 5);
#pragma unroll
            for (int r = 0; r < 16; ++r) {
                long row = rowb + (r & 3) + 8 * (r >> 2);
                out[row * NCOLS + col] = alpha * acc[mi][ni][r];
            }
        }
    }
#undef STAGE
}

// ---------------- host launch ----------------------------------------------------
extern "C" void kernel_launch(void* const* d_in, const int* in_sizes, int n_in,
                              void* d_out, int out_size, void* d_ws, size_t ws_size,
                              hipStream_t stream) {
    const float* x = (const float*)d_in[0];   // 8192 x 4096 f32
    const float* w = (const float*)d_in[1];   // 4096 x 4096 f32
    float* out = (float*)d_out;               // 8192 x 4096 f32

    uint8_t* ws = (uint8_t*)d_ws;
    signed char* Xq = (signed char*)ws;                  // fp4 ternary x, permuted (16 MB)
    signed char* Wq = (signed char*)(ws + XQ_BYTES);     // fp4 ternary w, permuted (8 MB)
    float* scal = (float*)(ws + SCAL_OFF);               // [delta_x, delta_w, alpha, pad]
    // partials at scal+4 (768 floats)

    k_reduce_abs<<<768, 256, 0, stream>>>(x, w, scal + 4);
    k_finalize<<<1, 256, 0, stream>>>(scal);
    k_quantF<<<6144, 256, 0, stream>>>(x, w, (uint4*)Xq, (uint4*)Wq, scal);
    k_gemm<<<512, 512, 0, stream>>>(Xq, Wq, out, scal);
}

// Round 8
// 153.751 us; speedup vs baseline: 1.1671x; 1.0168x over previous
//
#include <hip/hip_runtime.h>
#include <stdint.h>

typedef __attribute__((ext_vector_type(4))) int i32x4;
typedef __attribute__((ext_vector_type(16))) float f32x16;

#define MROWS 8192L
#define NCOLS 4096L
#define KDIM  4096L

#define XQ_BYTES   (MROWS * KDIM / 2)            // 16777216 (fp4, fragment-permuted)
#define WQ_BYTES   (NCOLS * KDIM / 2)            // 8388608
#define SCAL_OFF   (XQ_BYTES + WQ_BYTES)

// ---------------- reduction: sum|x| (blocks 0..511), sum|w| (blocks 512..767) ----
__global__ __launch_bounds__(256) void k_reduce_abs(const float* __restrict__ x,
                                                    const float* __restrict__ w,
                                                    float* __restrict__ partials) {
    __shared__ float sm[256];
    int b = blockIdx.x;
    int t = threadIdx.x;
    const float4* v;
    long base;
    if (b < 512) { v = (const float4*)x; base = (long)b * 16384; }
    else         { v = (const float4*)w; base = (long)(b - 512) * 16384; }
    float s = 0.f;
    for (int i = t; i < 16384; i += 256) {
        float4 q = v[base + i];
        s += fabsf(q.x) + fabsf(q.y) + fabsf(q.z) + fabsf(q.w);
    }
    sm[t] = s;
    __syncthreads();
    for (int off = 128; off > 0; off >>= 1) {
        if (t < off) sm[t] += sm[t + off];
        __syncthreads();
    }
    if (t == 0) partials[b] = sm[0];
}

// ---------------- finalize: double-precision combine, write scalars --------------
__global__ __launch_bounds__(256) void k_finalize(float* __restrict__ scal) {
    const float* partials = scal + 4;
    __shared__ double sm[256];
    int t = threadIdx.x;

    double sx = 0.0;
    for (int i = t; i < 512; i += 256) sx += (double)partials[i];
    sm[t] = sx;
    __syncthreads();
    for (int off = 128; off > 0; off >>= 1) {
        if (t < off) sm[t] += sm[t + off];
        __syncthreads();
    }
    double SX = sm[0];
    __syncthreads();

    double sw = (double)partials[512 + t];
    sm[t] = sw;
    __syncthreads();
    for (int off = 128; off > 0; off >>= 1) {
        if (t < off) sm[t] += sm[t + off];
        __syncthreads();
    }
    if (t == 0) {
        float meanx = (float)(SX / 33554432.0);
        float meanw = (float)(sm[0] / 16777216.0);
        scal[0] = 0.1f * meanx;   // delta_x
        scal[1] = 0.05f * meanw;  // delta_w
        scal[2] = meanw;          // alpha
    }
}

// ---------------- ternarize to fp4 e2m1 {-1,0,1}, fragment-permuted output -------
// Layout (X): 1KB block BX = (rowblk*32 + ktile)*2 + ks ; inside: [khalf(2)][r32(32)][16B]
__device__ __forceinline__ unsigned int nib4(float v, float delta) {
    return v > delta ? 2u : (v < -delta ? 10u : 0u);   // +1=0x2, -1=0xA, 0=0x0
}

__global__ __launch_bounds__(256) void k_quantF(const float* __restrict__ x,
                                                const float* __restrict__ w,
                                                uint4* __restrict__ xq,
                                                uint4* __restrict__ wq,
                                                const float* __restrict__ scal) {
    int wv = blockIdx.x * 4 + (threadIdx.x >> 6);   // wave task id, 0..24575
    int l = threadIdx.x & 63;

    const float* src;
    uint4* dst;
    float delta;
    int task;                        // block index within its tensor
    if (wv < 16384) {                // X: rowblk(256) x ktile(32) x ks(2)
        src = x; dst = xq; delta = scal[0]; task = wv;
    } else {                         // W: colblk(128) x ktile(32) x ks(2)
        src = w; dst = wq; delta = scal[1]; task = wv - 16384;
    }
    int rowblk = task >> 6;
    int rest = task & 63;            // ktile*2 + ks
    long row = (long)rowblk * 32 + (l & 31);
    long fidx = row * 4096 + (long)(rest >> 1) * 128 + (long)(rest & 1) * 64
              + (long)(l >> 5) * 32;
    const float4* s4 = (const float4*)(src + fidx);

    unsigned int ow[4];
#pragma unroll
    for (int c = 0; c < 4; ++c) {
        float4 q0 = s4[2 * c];
        float4 q1 = s4[2 * c + 1];
        ow[c] = nib4(q0.x, delta)
              | (nib4(q0.y, delta) << 4)
              | (nib4(q0.z, delta) << 8)
              | (nib4(q0.w, delta) << 12)
              | (nib4(q1.x, delta) << 16)
              | (nib4(q1.y, delta) << 20)
              | (nib4(q1.z, delta) << 24)
              | (nib4(q1.w, delta) << 28);
    }
    uint4 o; o.x = ow[0]; o.y = ow[1]; o.z = ow[2]; o.w = ow[3];
    dst[(long)task * 64 + l] = o;    // 64 lanes x 16B = contiguous 1KB
}

// ---- GEMM: out = alpha * (Xq @ Wq^T), fp4 32x32x64, BK=128 double-groups --------
#define GLOAD_LDS16(g, l)                                                             \
    __builtin_amdgcn_global_load_lds((const __attribute__((address_space(1))) void*)(g), \
                                     (__attribute__((address_space(3))) void*)(l),       \
                                     16, 0, 0)

// i32x4 -> i32x8 with undef high half (fp4 data occupies low 4 VGPRs)
#define MK8(v) __builtin_shufflevector((v), (v), 0, 1, 2, 3, -1, -1, -1, -1)

// fp4 x fp4, scales = 1.0 (E8M0 127 in every byte)
#define MFMA32(a, b, c)                                                       \
    __builtin_amdgcn_mfma_scale_f32_32x32x64_f8f6f4(MK8(a), MK8(b), (c),      \
        4, 4, 0, 0x7F7F7F7F, 0, 0x7F7F7F7F)

__global__ __launch_bounds__(512, 2) void k_gemm(const signed char* __restrict__ Xq,
                                                 const signed char* __restrict__ Wq,
                                                 float* __restrict__ out,
                                                 const float* __restrict__ scal) {
    // ring of 4 K-tile slots, each 32 KB fragment-major:
    //   A groups g=0..15:  [wm(2)][mi(4)][ks(2)] x (64 lanes x 16 B)
    //   B groups g=16..31: [wn(4)][ni(2)][ks(2)] x (64 lanes x 16 B)
    __shared__ __attribute__((aligned(16))) signed char lds[131072];

    const float alpha = scal[2];

    // XCD-aware bijective swizzle (512 blocks, 512 % 8 == 0, cpx = 64)
    int bid = (int)blockIdx.x;
    bid = (bid & 7) * 64 + (bid >> 3);
    int bm = bid >> 4;                 // 0..31  (M/256)
    int bn = bid & 15;                 // 0..15  (N/256)
    long row0 = (long)bm * 256;
    long col0 = (long)bn * 256;

    int t = threadIdx.x;               // 0..511
    int lane = t & 63;
    int wid = t >> 6;                  // 0..7
    int wm = wid >> 2;                 // 0..1  (M half: 128 rows)
    int wn = wid & 3;                  // 0..3  (N quarter: 64 cols)

    // ---- staging: each wave stages 4 fragment groups (g = wid*4 + j) ----
    // source is PRE-PERMUTED: block (rowblk*32 + g1)*2 + ks, lane-contiguous 1KB
    const signed char* sp[4];
    int ldoff[4];
#pragma unroll
    for (int j = 0; j < 4; ++j) {
        int g = wid * 4 + j;
        ldoff[j] = g * 1024;
        if (g < 16) {   // A: wm=g>>3, mi=(g>>1)&3, ks=g&1
            long rowblk = bm * 8 + (g >> 3) * 4 + ((g >> 1) & 3);
            sp[j] = Xq + rowblk * 65536 + (g & 1) * 1024 + lane * 16;
        } else {        // B: h=g-16, wn=h>>2, ni=(h>>1)&1, ks=h&1
            int h = g - 16;
            long colblk = bn * 8 + (h >> 2) * 2 + ((h >> 1) & 1);
            sp[j] = Wq + colblk * 65536 + (h & 1) * 1024 + lane * 16;
        }
    }

#define STAGE(slot, g1) do {                                                   \
    signed char* sb_ = lds + (slot) * 32768;                                   \
    _Pragma("unroll")                                                          \
    for (int j_ = 0; j_ < 4; ++j_)                                             \
        GLOAD_LDS16(sp[j_] + (long)(g1) * 2048, sb_ + ldoff[j_]);              \
} while (0)

    // ---- fragment read addressing: uniform base + lane*16 + imm offset ----
    const signed char* Ab = lds + wm * 8192 + lane * 16;            // + slot*32768 + (mi*2+ks)*1024
    const signed char* Bb = lds + 16384 + wn * 4096 + lane * 16;    // + slot*32768 + (ni*2+ks)*1024

    f32x16 acc[4][2];
#pragma unroll
    for (int i = 0; i < 4; ++i)
#pragma unroll
        for (int j = 0; j < 2; ++j)
            acc[i][j] = (f32x16){0.f};

    // interleaved read->MFMA body for one K-tile slot (reads hide under quads)
#define BODY(slot) do {                                                        \
    const signed char* A = Ab + (slot) * 32768;                                \
    const signed char* B = Bb + (slot) * 32768;                                \
    i32x4 b00 = *(const i32x4*)(B + 0 * 1024);                                 \
    i32x4 b10 = *(const i32x4*)(B + 2 * 1024);                                 \
    i32x4 a00 = *(const i32x4*)(A + 0 * 1024);                                 \
    i32x4 a10 = *(const i32x4*)(A + 2 * 1024);                                 \
    acc[0][0] = MFMA32(a00, b00, acc[0][0]);                                   \
    acc[1][0] = MFMA32(a10, b00, acc[1][0]);                                   \
    acc[0][1] = MFMA32(a00, b10, acc[0][1]);                                   \
    acc[1][1] = MFMA32(a10, b10, acc[1][1]);                                   \
    i32x4 b01 = *(const i32x4*)(B + 1 * 1024);                                 \
    i32x4 b11 = *(const i32x4*)(B + 3 * 1024);                                 \
    i32x4 a01 = *(const i32x4*)(A + 1 * 1024);                                 \
    i32x4 a11 = *(const i32x4*)(A + 3 * 1024);                                 \
    acc[0][0] = MFMA32(a01, b01, acc[0][0]);                                   \
    acc[1][0] = MFMA32(a11, b01, acc[1][0]);                                   \
    acc[0][1] = MFMA32(a01, b11, acc[0][1]);                                   \
    acc[1][1] = MFMA32(a11, b11, acc[1][1]);                                   \
    i32x4 a20 = *(const i32x4*)(A + 4 * 1024);                                 \
    i32x4 a30 = *(const i32x4*)(A + 6 * 1024);                                 \
    acc[2][0] = MFMA32(a20, b00, acc[2][0]);                                   \
    acc[3][0] = MFMA32(a30, b00, acc[3][0]);                                   \
    acc[2][1] = MFMA32(a20, b10, acc[2][1]);                                   \
    acc[3][1] = MFMA32(a30, b10, acc[3][1]);                                   \
    i32x4 a21 = *(const i32x4*)(A + 5 * 1024);                                 \
    i32x4 a31 = *(const i32x4*)(A + 7 * 1024);                                 \
    acc[2][0] = MFMA32(a21, b01, acc[2][0]);                                   \
    acc[3][0] = MFMA32(a31, b01, acc[3][0]);                                   \
    acc[2][1] = MFMA32(a21, b11, acc[2][1]);                                   \
    acc[3][1] = MFMA32(a31, b11, acc[3][1]);                                   \
} while (0)

    // prologue: stage K-tiles 0,1 into slots 0,1 (8 loads in flight)
    STAGE(0, 0);
    STAGE(1, 1);

    // 16 double-groups, each covering K-tiles 2d, 2d+1 (BK=128)
    for (int d = 0; d < 16; ++d) {
        int s0 = (2 * d) & 3;
        int s1 = (2 * d + 1) & 3;
        // B1: all waves done with bodies of group d-1 -> its slot pair is free
        __builtin_amdgcn_s_barrier();
        if (d < 15) {
            STAGE((2 * d + 2) & 3, 2 * d + 2);                     // issue-early
            STAGE((2 * d + 3) & 3, 2 * d + 3);
            asm volatile("s_waitcnt vmcnt(8)" ::: "memory");       // pair d landed
        } else {
            asm volatile("s_waitcnt vmcnt(0)" ::: "memory");       // final drain
        }
        // B2: publish "pair d fully landed" to all waves
        __builtin_amdgcn_s_barrier();
        __builtin_amdgcn_sched_barrier(0);

        BODY(s0);
        BODY(s1);
    }

    // epilogue: 32x32 C/D mapping: col = lane&31, row = (r&3) + 8*(r>>2) + 4*(lane>>5)
#pragma unroll
    for (int mi = 0; mi < 4; ++mi) {
#pragma unroll
        for (int ni = 0; ni < 2; ++ni) {
            long col = col0 + wn * 64 + ni * 32 + (lane & 31);
            long rowb = row0 + wm * 128 + mi * 32 + 4 * (lane >> 5);
#pragma unroll
            for (int r = 0; r < 16; ++r) {
                long row = rowb + (r & 3) + 8 * (r >> 2);
                out[row * NCOLS + col] = alpha * acc[mi][ni][r];
            }
        }
    }
#undef BODY
#undef STAGE
}

// ---------------- host launch ----------------------------------------------------
extern "C" void kernel_launch(void* const* d_in, const int* in_sizes, int n_in,
                              void* d_out, int out_size, void* d_ws, size_t ws_size,
                              hipStream_t stream) {
    const float* x = (const float*)d_in[0];   // 8192 x 4096 f32
    const float* w = (const float*)d_in[1];   // 4096 x 4096 f32
    float* out = (float*)d_out;               // 8192 x 4096 f32

    uint8_t* ws = (uint8_t*)d_ws;
    signed char* Xq = (signed char*)ws;                  // fp4 ternary x, permuted (16 MB)
    signed char* Wq = (signed char*)(ws + XQ_BYTES);     // fp4 ternary w, permuted (8 MB)
    float* scal = (float*)(ws + SCAL_OFF);               // [delta_x, delta_w, alpha, pad]
    // partials at scal+4 (768 floats)

    k_reduce_abs<<<768, 256, 0, stream>>>(x, w, scal + 4);
    k_finalize<<<1, 256, 0, stream>>>(scal);
    k_quantF<<<6144, 256, 0, stream>>>(x, w, (uint4*)Xq, (uint4*)Wq, scal);
    k_gemm<<<512, 512, 0, stream>>>(Xq, Wq, out, scal);
}